// Round 4
// baseline (1835.202 us; speedup 1.0000x reference)
//
#include <hip/hip_runtime.h>
#include <hip/hip_bf16.h>

typedef __hip_bfloat16 bf16;

constexpr int B_ = 32, S_ = 8, H_ = 32, W_ = 32, C_ = 128;
constexpr int NH_ = 8, KD_ = 512, DKH_ = 64, VF_ = 128, OF_ = 64;
constexpr int QKIN_ = 8192; // (H/4)*(W/4)*C

// ---------------- zero fp32 region
__global__ void k_zero(float* __restrict__ p, int n) {
    int i = blockIdx.x * 256 + threadIdx.x;
    if (i < n) p[i] = 0.f;
}

// ---------------- avg pool 4x4 -> flattened (img, 8192) fp32
__global__ void k_pool(const float* __restrict__ in, float* __restrict__ out, int n_img) {
    int idx = blockIdx.x * 256 + threadIdx.x;
    if (idx >= n_img * QKIN_) return;
    int c  = idx & 127;
    int pw = (idx >> 7) & 7;
    int ph = (idx >> 10) & 7;
    int img = idx >> 13;
    const float* p = in + (((size_t)img * H_ + ph * 4) * W_ + pw * 4) * C_ + c;
    float s = 0.f;
#pragma unroll
    for (int dy = 0; dy < 4; ++dy)
#pragma unroll
        for (int dx = 0; dx < 4; ++dx)
            s += p[(dy * W_ + dx) * C_];
    out[idx] = s * 0.0625f;
}

// ---------------- split-K GEMM: out[row,co] += sum_k a[row,k]*w[k,co]  (atomics)
template <int R, int KSL>
__global__ void k_gemm(const float* __restrict__ a, const float* __restrict__ w,
                       float* __restrict__ out) {
    __shared__ float lds[R][KSL];  // 32 KB
    const int co = threadIdx.x;    // 512 threads = 512 output cols
    const int rg = blockIdx.x;
    const int k0 = blockIdx.y * KSL;
    float acc[R];
#pragma unroll
    for (int r = 0; r < R; ++r) acc[r] = 0.f;
    for (int i = threadIdx.x; i < R * KSL; i += 512)
        lds[i / KSL][i % KSL] = a[((size_t)(rg * R + i / KSL)) * QKIN_ + k0 + (i % KSL)];
    __syncthreads();
    for (int kk = 0; kk < KSL; ++kk) {
        float wv = w[(size_t)(k0 + kk) * KD_ + co];
#pragma unroll
        for (int r = 0; r < R; ++r)
            acc[r] = fmaf(lds[r][kk], wv, acc[r]);
    }
#pragma unroll
    for (int r = 0; r < R; ++r)
        atomicAdd(&out[((size_t)(rg * R + r)) * KD_ + co], acc[r]);
}

// ---------------- logits + softmax -> weights (B, NH, S) fp32
__global__ void k_attnw(const float* __restrict__ q, const float* __restrict__ k,
                        const float* __restrict__ table_k, float* __restrict__ wt) {
    int b = blockIdx.x;
    int t = threadIdx.x;            // 64 = 8 heads x 8 keys
    int h = t >> 3, s = t & 7;
    int zi = (s < 4) ? 0 : (s - 4); // clip(k-7,-3,3)+3 -> [0,0,0,0,0,1,2,3]
    const float* qp = q + (size_t)b * KD_ + h * DKH_;
    const float* kp = k + ((size_t)b * S_ + s) * KD_ + h * DKH_;
    const float* zp = table_k + (size_t)zi * DKH_;
    float dot = 0.f;
    for (int d = 0; d < DKH_; ++d)
        dot += qp[d] * (kp[d] + zp[d]);
    dot *= 0.125f; // 64^-0.5
    float m = dot;
    for (int msk = 1; msk < 8; msk <<= 1) m = fmaxf(m, __shfl_xor(m, msk));
    float e = expf(dot - m);
    float sum = e;
    for (int msk = 1; msk < 8; msk <<= 1) sum += __shfl_xor(sum, msk);
    wt[((size_t)b * NH_ + h) * S_ + s] = e / sum;
}

// ---------------- fused: attention-mix of v_ant rows -> smem, conv_v 3x3, + bias
// ---------------- + z_v epilogue -> x (bf16).  Block = (b, h, jout); out row y=4h+jout.
__global__ __launch_bounds__(256) void k_convv(
    const float* __restrict__ v_ant, const float* __restrict__ wf,
    const float* __restrict__ bias, const float* __restrict__ table_v,
    const float* __restrict__ wt, bf16* __restrict__ x) {
    __shared__ float smem[3][C_][W_ + 1];  // [ky][ci][px]
    int blk = blockIdx.x;                  // b*32 + h*4 + jout
    int jout = blk & 3;
    int h = (blk >> 2) & 7;
    int b = blk >> 5;
    int y = 4 * h + jout;
    const float* wtb = wt + ((size_t)(b * NH_ + h)) * S_;
    float w8[8];
#pragma unroll
    for (int kk = 0; kk < 8; ++kk) w8[kk] = wtb[kk];
#pragma unroll
    for (int ky = 0; ky < 3; ++ky) {
        int r = y + ky - 1;
        if (r < 0 || r >= H_) {
            for (int i = threadIdx.x; i < W_ * C_; i += 256)
                smem[ky][i & 127][i >> 7] = 0.f;
        } else {
            const float* base = v_ant + ((size_t)b * S_ * H_ + r) * W_ * C_;
            for (int i = threadIdx.x; i < W_ * C_; i += 256) {
                float s = 0.f;
#pragma unroll
                for (int kk = 0; kk < 8; ++kk)
                    s += w8[kk] * base[(size_t)kk * H_ * W_ * C_ + i];
                smem[ky][i & 127][i >> 7] = s;
            }
        }
    }
    __syncthreads();
    int px = threadIdx.x >> 3;
    int co0 = (threadIdx.x & 7) * 16;
    float acc[16];
#pragma unroll
    for (int j = 0; j < 16; ++j) acc[j] = 0.f;
    for (int ci = 0; ci < C_; ++ci) {
        float iv[9];
#pragma unroll
        for (int ky = 0; ky < 3; ++ky) {
            iv[ky * 3 + 0] = (px > 0) ? smem[ky][ci][px - 1] : 0.f;
            iv[ky * 3 + 1] = smem[ky][ci][px];
            iv[ky * 3 + 2] = (px < W_ - 1) ? smem[ky][ci][px + 1] : 0.f;
        }
#pragma unroll
        for (int tap = 0; tap < 9; ++tap) {
            const float4* wp =
                reinterpret_cast<const float4*>(wf + ((size_t)tap * C_ + ci) * VF_ + co0);
            float v = iv[tap];
#pragma unroll
            for (int q4 = 0; q4 < 4; ++q4) {
                float4 wv = wp[q4];
                acc[q4 * 4 + 0] = fmaf(v, wv.x, acc[q4 * 4 + 0]);
                acc[q4 * 4 + 1] = fmaf(v, wv.y, acc[q4 * 4 + 1]);
                acc[q4 * 4 + 2] = fmaf(v, wv.z, acc[q4 * 4 + 2]);
                acc[q4 * 4 + 3] = fmaf(v, wv.w, acc[q4 * 4 + 3]);
            }
        }
    }
    // epilogue: + bias + sum_k wt[k] * table_v[[0,0,0,0,0,1,2,3][k], d]
    float cw[4];
    cw[0] = w8[0] + w8[1] + w8[2] + w8[3] + w8[4];
    cw[1] = w8[5];
    cw[2] = w8[6];
    cw[3] = w8[7];
    int dbase = jout * 4096 + px * 128 + co0;   // d within head: (jout, px, c)
#pragma unroll
    for (int zi = 0; zi < 4; ++zi) {
        const float* tv = table_v + (size_t)zi * 16384 + dbase;
        float c = cw[zi];
#pragma unroll
        for (int j = 0; j < 16; ++j)
            acc[j] = fmaf(c, tv[j], acc[j]);
    }
    bf16* xo = x + (((size_t)b * H_ + y) * W_ + px) * C_ + co0;
#pragma unroll
    for (int j = 0; j < 16; ++j)
        xo[j] = __float2bfloat16(acc[j] + bias[co0 + j]);
}

// ---------------- conv_o (3x3 SAME, 128 -> 64) + bias -> fp32 out
__global__ __launch_bounds__(256) void k_convo(
    const bf16* __restrict__ x, const float* __restrict__ wf,
    const float* __restrict__ bias, float* __restrict__ out) {
    __shared__ float smem[3][C_][W_ + 1];
    int blk = blockIdx.x;  // b*32 + y
    int y = blk & 31;
    int b = blk >> 5;
#pragma unroll
    for (int ky = 0; ky < 3; ++ky) {
        int yy = y + ky - 1;
        if (yy < 0 || yy >= H_) {
            for (int i = threadIdx.x; i < W_ * C_; i += 256)
                smem[ky][i & 127][i >> 7] = 0.f;
        } else {
            const bf16* src = x + ((size_t)b * H_ + yy) * W_ * C_;
            for (int i = threadIdx.x; i < W_ * C_; i += 256)
                smem[ky][i & 127][i >> 7] = __bfloat162float(src[i]);
        }
    }
    __syncthreads();
    int px = threadIdx.x >> 3;
    int co0 = (threadIdx.x & 7) * 8;
    float acc[8];
#pragma unroll
    for (int j = 0; j < 8; ++j) acc[j] = 0.f;
    for (int ci = 0; ci < C_; ++ci) {
        float iv[9];
#pragma unroll
        for (int ky = 0; ky < 3; ++ky) {
            iv[ky * 3 + 0] = (px > 0) ? smem[ky][ci][px - 1] : 0.f;
            iv[ky * 3 + 1] = smem[ky][ci][px];
            iv[ky * 3 + 2] = (px < W_ - 1) ? smem[ky][ci][px + 1] : 0.f;
        }
#pragma unroll
        for (int tap = 0; tap < 9; ++tap) {
            const float4* wp =
                reinterpret_cast<const float4*>(wf + ((size_t)tap * C_ + ci) * OF_ + co0);
            float v = iv[tap];
#pragma unroll
            for (int q4 = 0; q4 < 2; ++q4) {
                float4 wv = wp[q4];
                acc[q4 * 4 + 0] = fmaf(v, wv.x, acc[q4 * 4 + 0]);
                acc[q4 * 4 + 1] = fmaf(v, wv.y, acc[q4 * 4 + 1]);
                acc[q4 * 4 + 2] = fmaf(v, wv.z, acc[q4 * 4 + 2]);
                acc[q4 * 4 + 3] = fmaf(v, wv.w, acc[q4 * 4 + 3]);
            }
        }
    }
    float* o = out + (((size_t)b * H_ + y) * W_ + px) * OF_ + co0;
#pragma unroll
    for (int j = 0; j < 8; ++j)
        o[j] = acc[j] + bias[co0 + j];
}

extern "C" void kernel_launch(void* const* d_in, const int* in_sizes, int n_in,
                              void* d_out, int out_size, void* d_ws, size_t ws_size,
                              hipStream_t stream) {
    const float* inp   = (const float*)d_in[0];
    const float* k_ant = (const float*)d_in[1];
    const float* v_ant = (const float*)d_in[2];
    const float* w_q   = (const float*)d_in[3];
    const float* w_k   = (const float*)d_in[4];
    const float* cvw   = (const float*)d_in[5];
    const float* cvb   = (const float*)d_in[6];
    const float* cow   = (const float*)d_in[7];
    const float* cob   = (const float*)d_in[8];
    const float* tbk   = (const float*)d_in[9];
    const float* tbv   = (const float*)d_in[10];

    // ws layout (bytes) — total ~13.9 MB
    char* wsb = (char*)d_ws;
    float* q    = (float*)(wsb + 0);         //   16384 f32 (64 KB)
    float* k    = (float*)(wsb + 65536);     //  131072 f32 (512 KB)
    float* wt   = (float*)(wsb + 589824);    //    2048 f32 (8 KB)
    float* q_a  = (float*)(wsb + 598016);    //  262144 f32 (1 MB)
    float* k_a  = (float*)(wsb + 1646592);   // 2097152 f32 (8 MB)
    bf16*  x    = (bf16*)(wsb + 10035200);   // 4194304 bf16 (8 MB) end ~18.4MB? no:
    // 10035200 + 8388608 = 18423808 bytes ≈ 17.6 MB total -- keep x bf16 = 4MB:
    // 10035200 + 4194304*2 = 18423808. (x is bf16: 4194304 elems * 2 B = 8 MB)
    // Correction: 4194304 bf16 = 8388608 bytes; total 18423808 B ≈ 17.6 MB.

    k_zero<<<576, 256, 0, stream>>>(q, 147456);   // zeros q (16384) + k (131072), contiguous
    k_pool<<<1024, 256, 0, stream>>>(inp, q_a, 32);
    k_pool<<<8192, 256, 0, stream>>>(k_ant, k_a, 256);
    k_gemm<32, 256><<<dim3(1, 32), 512, 0, stream>>>(q_a, w_q, q);
    k_gemm<32, 256><<<dim3(8, 32), 512, 0, stream>>>(k_a, w_k, k);
    k_attnw<<<32, 64, 0, stream>>>(q, k, tbk, wt);
    k_convv<<<1024, 256, 0, stream>>>(v_ant, cvw, cvb, tbv, wt, x);
    k_convo<<<1024, 256, 0, stream>>>(x, cow, cob, (float*)d_out);
}

// Round 5
// 710.074 us; speedup vs baseline: 2.5845x; 2.5845x over previous
//
#include <hip/hip_runtime.h>
#include <hip/hip_bf16.h>

typedef __hip_bfloat16 bf16;
typedef __attribute__((ext_vector_type(8))) short bf16x8;
typedef __attribute__((ext_vector_type(4))) float f32x4;

constexpr int B_ = 32, S_ = 8, H_ = 32, W_ = 32, C_ = 128;
constexpr int NH_ = 8, KD_ = 512, DKH_ = 64, VF_ = 128, OF_ = 64;
constexpr int QKIN_ = 8192;

static __device__ __forceinline__ short bfbits(float f) {
    bf16 h = __float2bfloat16(f);
    short s;
    __builtin_memcpy(&s, &h, 2);
    return s;
}
static __device__ __forceinline__ unsigned int packbf2(float a, float b) {
    return ((unsigned int)(unsigned short)bfbits(b) << 16) | (unsigned short)bfbits(a);
}

// ---------------- zero fp32 region
__global__ void k_zero(float* __restrict__ p, int n) {
    int i = blockIdx.x * 256 + threadIdx.x;
    if (i < n) p[i] = 0.f;
}

// ---------------- avg pool 4x4 -> flattened (img, 8192) fp32
__global__ void k_pool(const float* __restrict__ in, float* __restrict__ out, int n_img) {
    int idx = blockIdx.x * 256 + threadIdx.x;
    if (idx >= n_img * QKIN_) return;
    int c  = idx & 127;
    int pw = (idx >> 7) & 7;
    int ph = (idx >> 10) & 7;
    int img = idx >> 13;
    const float* p = in + (((size_t)img * H_ + ph * 4) * W_ + pw * 4) * C_ + c;
    float s = 0.f;
#pragma unroll
    for (int dy = 0; dy < 4; ++dy)
#pragma unroll
        for (int dx = 0; dx < 4; ++dx)
            s += p[(dy * W_ + dx) * C_];
    out[idx] = s * 0.0625f;
}

// ---------------- split-K projection, 4x4 register tile, float4 loads, atomics
// grid (mblk, 4, 8), block 256. out rows = mblk*32, cols 512, K=8192 split by 8.
__global__ __launch_bounds__(256) void k_proj(const float* __restrict__ a,
                                              const float* __restrict__ w,
                                              float* __restrict__ out) {
    int r0  = blockIdx.x * 32 + (threadIdx.x >> 5) * 4;
    int co0 = blockIdx.y * 128 + (threadIdx.x & 31) * 4;
    int k0  = blockIdx.z * 1024;
    float acc[4][4];
#pragma unroll
    for (int r = 0; r < 4; ++r)
#pragma unroll
        for (int c = 0; c < 4; ++c) acc[r][c] = 0.f;
    for (int kk = k0; kk < k0 + 1024; kk += 4) {
        float4 av[4], wv[4];
#pragma unroll
        for (int r = 0; r < 4; ++r)
            av[r] = *reinterpret_cast<const float4*>(a + (size_t)(r0 + r) * QKIN_ + kk);
#pragma unroll
        for (int j = 0; j < 4; ++j)
            wv[j] = *reinterpret_cast<const float4*>(w + (size_t)(kk + j) * KD_ + co0);
#pragma unroll
        for (int r = 0; r < 4; ++r) {
            const float* ar = reinterpret_cast<const float*>(&av[r]);
#pragma unroll
            for (int j = 0; j < 4; ++j) {
                float4 wj = wv[j];
                acc[r][0] = fmaf(ar[j], wj.x, acc[r][0]);
                acc[r][1] = fmaf(ar[j], wj.y, acc[r][1]);
                acc[r][2] = fmaf(ar[j], wj.z, acc[r][2]);
                acc[r][3] = fmaf(ar[j], wj.w, acc[r][3]);
            }
        }
    }
#pragma unroll
    for (int r = 0; r < 4; ++r)
#pragma unroll
        for (int c = 0; c < 4; ++c)
            atomicAdd(&out[(size_t)(r0 + r) * KD_ + co0 + c], acc[r][c]);
}

// ---------------- logits + softmax -> weights (B, NH, S) fp32
__global__ void k_attnw(const float* __restrict__ q, const float* __restrict__ k,
                        const float* __restrict__ table_k, float* __restrict__ wt) {
    int b = blockIdx.x;
    int t = threadIdx.x;
    int h = t >> 3, s = t & 7;
    int zi = (s < 4) ? 0 : (s - 4);
    const float* qp = q + (size_t)b * KD_ + h * DKH_;
    const float* kp = k + ((size_t)b * S_ + s) * KD_ + h * DKH_;
    const float* zp = table_k + (size_t)zi * DKH_;
    float dot = 0.f;
    for (int d = 0; d < DKH_; ++d)
        dot += qp[d] * (kp[d] + zp[d]);
    dot *= 0.125f;
    float m = dot;
    for (int msk = 1; msk < 8; msk <<= 1) m = fmaxf(m, __shfl_xor(m, msk));
    float e = expf(dot - m);
    float sum = e;
    for (int msk = 1; msk < 8; msk <<= 1) sum += __shfl_xor(sum, msk);
    wt[((size_t)b * NH_ + h) * S_ + s] = e / sum;
}

// ---------------- conv weight transpose: [tap][ci][CO] f32 -> [tap][co][CI] bf16
template <int CO>
__global__ void k_wtrans(const float* __restrict__ in, short* __restrict__ out) {
    int idx = blockIdx.x * 256 + threadIdx.x;
    if (idx >= 9 * 128 * CO) return;
    int tap = idx / (128 * CO);
    int rem = idx % (128 * CO);
    int co = rem / 128;
    int ci = rem % 128;
    out[idx] = bfbits(in[((size_t)tap * 128 + ci) * CO + co]);
}

// ---------------- fused mix + conv_v via MFMA. block=(b,h), 4 waves.
// strip LDS: 6 rows x 32 px x 128 ci bf16, row-pitch 136 shorts (bank-spread).
__global__ __launch_bounds__(256) void k_convv_mfma(
    const float* __restrict__ v_ant, const short* __restrict__ wvT,
    const float* __restrict__ bias, const float* __restrict__ tbv,
    const float* __restrict__ wt, short* __restrict__ x) {
    __shared__ short strip[6 * 32 * 136];  // 52224 B
    int b = blockIdx.x >> 3, h = blockIdx.x & 7;
    int y0 = 4 * h;
    const float* wtb = wt + (size_t)(b * NH_ + h) * S_;
    float w8[8];
#pragma unroll
    for (int kk = 0; kk < 8; ++kk) w8[kk] = wtb[kk];
    // phase 1: softmax-mix 6 halo rows -> bf16 strip (pairs)
    for (int i = threadIdx.x; i < 6 * 2048; i += 256) {
        int r = i >> 11, rem2 = i & 2047;          // rem2 = px*64 + ci/2
        int yimg = y0 - 1 + r;
        float s0 = 0.f, s1 = 0.f;
        if (0 <= yimg && yimg < H_) {
            const float* base = v_ant + (size_t)b * 1048576 + yimg * 4096 + rem2 * 2;
#pragma unroll
            for (int kk = 0; kk < 8; ++kk) {
                float2 v = *reinterpret_cast<const float2*>(base + (size_t)kk * 131072);
                s0 = fmaf(w8[kk], v.x, s0);
                s1 = fmaf(w8[kk], v.y, s1);
            }
        }
        int px = rem2 >> 6, cp = rem2 & 63;
        *reinterpret_cast<unsigned int*>(&strip[(r * 32 + px) * 136 + cp * 2]) =
            packbf2(s0, s1);
    }
    __syncthreads();
    // phase 2: GEMM M=128(4 rows x 32 px), N=128 co, K=1152
    int wave = threadIdx.x >> 6, lane = threadIdx.x & 63;
    int quad = lane >> 4, l15 = lane & 15;
    int n0 = wave * 32;
    f32x4 acc[8][2];
#pragma unroll
    for (int mt = 0; mt < 8; ++mt)
#pragma unroll
        for (int nt = 0; nt < 2; ++nt) acc[mt][nt] = (f32x4){0.f, 0.f, 0.f, 0.f};
    const bf16x8 zero8 = (bf16x8)0;
    for (int kc = 0; kc < 36; ++kc) {
        int tap = kc >> 2;
        int ci0 = (kc & 3) * 32 + quad * 8;
        int ky = tap / 3, dx = tap % 3;
        bf16x8 bfr[2];
#pragma unroll
        for (int nt = 0; nt < 2; ++nt) {
            int co = n0 + nt * 16 + l15;
            bfr[nt] = *reinterpret_cast<const bf16x8*>(
                wvT + ((size_t)tap * 128 + co) * 128 + ci0);
        }
#pragma unroll
        for (int mt = 0; mt < 8; ++mt) {
            int jout = mt >> 1, half = mt & 1;
            int r = jout + ky;
            int pxg = half * 16 + l15 + dx - 1;
            bf16x8 afr = zero8;
            if (pxg >= 0 && pxg < 32)
                afr = *reinterpret_cast<const bf16x8*>(
                    &strip[(r * 32 + pxg) * 136 + ci0]);
            acc[mt][0] = __builtin_amdgcn_mfma_f32_16x16x32_bf16(afr, bfr[0], acc[mt][0], 0, 0, 0);
            acc[mt][1] = __builtin_amdgcn_mfma_f32_16x16x32_bf16(afr, bfr[1], acc[mt][1], 0, 0, 0);
        }
    }
    // epilogue: + bias + z_v (4 weighted table rows), write x bf16
    float cw[4];
    cw[0] = w8[0] + w8[1] + w8[2] + w8[3] + w8[4];
    cw[1] = w8[5];
    cw[2] = w8[6];
    cw[3] = w8[7];
#pragma unroll
    for (int mt = 0; mt < 8; ++mt) {
        int jout = mt >> 1, half = mt & 1;
#pragma unroll
        for (int nt = 0; nt < 2; ++nt) {
            int co = n0 + nt * 16 + l15;
            float bv = bias[co];
#pragma unroll
            for (int reg = 0; reg < 4; ++reg) {
                int px = half * 16 + quad * 4 + reg;
                int d = jout * 4096 + px * 128 + co;
                float v = acc[mt][nt][reg] + bv;
                v = fmaf(cw[0], tbv[d], v);
                v = fmaf(cw[1], tbv[16384 + d], v);
                v = fmaf(cw[2], tbv[32768 + d], v);
                v = fmaf(cw[3], tbv[49152 + d], v);
                x[(((size_t)b * H_ + y0 + jout) * W_ + px) * C_ + co] = bfbits(v);
            }
        }
    }
}

// ---------------- conv_o via MFMA. block=(b, rowgroup of 4), 4 waves (one n-tile each).
__global__ __launch_bounds__(256) void k_convo_mfma(
    const short* __restrict__ x, const short* __restrict__ woT,
    const float* __restrict__ bias, float* __restrict__ out) {
    __shared__ short strip[6 * 32 * 136];
    int b = blockIdx.x >> 3, rg = blockIdx.x & 7;
    int y0 = 4 * rg;
    for (int i = threadIdx.x; i < 6 * 2048; i += 256) {
        int r = i >> 11, rem2 = i & 2047;
        int yimg = y0 - 1 + r;
        unsigned int v = 0;
        if (0 <= yimg && yimg < H_)
            v = *reinterpret_cast<const unsigned int*>(
                x + (size_t)b * 131072 + yimg * 4096 + rem2 * 2);
        int px = rem2 >> 6, cp = rem2 & 63;
        *reinterpret_cast<unsigned int*>(&strip[(r * 32 + px) * 136 + cp * 2]) = v;
    }
    __syncthreads();
    int wave = threadIdx.x >> 6, lane = threadIdx.x & 63;
    int quad = lane >> 4, l15 = lane & 15;
    int co = wave * 16 + l15;
    f32x4 acc[8];
#pragma unroll
    for (int mt = 0; mt < 8; ++mt) acc[mt] = (f32x4){0.f, 0.f, 0.f, 0.f};
    const bf16x8 zero8 = (bf16x8)0;
    for (int kc = 0; kc < 36; ++kc) {
        int tap = kc >> 2;
        int ci0 = (kc & 3) * 32 + quad * 8;
        int ky = tap / 3, dx = tap % 3;
        bf16x8 bfr = *reinterpret_cast<const bf16x8*>(
            woT + ((size_t)tap * 64 + co) * 128 + ci0);
#pragma unroll
        for (int mt = 0; mt < 8; ++mt) {
            int jout = mt >> 1, half = mt & 1;
            int r = jout + ky;
            int pxg = half * 16 + l15 + dx - 1;
            bf16x8 afr = zero8;
            if (pxg >= 0 && pxg < 32)
                afr = *reinterpret_cast<const bf16x8*>(
                    &strip[(r * 32 + pxg) * 136 + ci0]);
            acc[mt] = __builtin_amdgcn_mfma_f32_16x16x32_bf16(afr, bfr, acc[mt], 0, 0, 0);
        }
    }
    float bv = bias[co];
#pragma unroll
    for (int mt = 0; mt < 8; ++mt) {
        int jout = mt >> 1, half = mt & 1;
#pragma unroll
        for (int reg = 0; reg < 4; ++reg) {
            int px = half * 16 + quad * 4 + reg;
            out[(((size_t)b * H_ + y0 + jout) * W_ + px) * OF_ + co] = acc[mt][reg] + bv;
        }
    }
}

extern "C" void kernel_launch(void* const* d_in, const int* in_sizes, int n_in,
                              void* d_out, int out_size, void* d_ws, size_t ws_size,
                              hipStream_t stream) {
    const float* inp   = (const float*)d_in[0];
    const float* k_ant = (const float*)d_in[1];
    const float* v_ant = (const float*)d_in[2];
    const float* w_q   = (const float*)d_in[3];
    const float* w_k   = (const float*)d_in[4];
    const float* cvw   = (const float*)d_in[5];
    const float* cvb   = (const float*)d_in[6];
    const float* cow   = (const float*)d_in[7];
    const float* cob   = (const float*)d_in[8];
    const float* tbk   = (const float*)d_in[9];
    const float* tbv   = (const float*)d_in[10];

    // ws layout (bytes), total ~18.0 MB
    char* wsb = (char*)d_ws;
    float* q    = (float*)(wsb + 0);         //   16384 f32
    float* k    = (float*)(wsb + 65536);     //  131072 f32
    float* wt   = (float*)(wsb + 589824);    //    2048 f32
    float* q_a  = (float*)(wsb + 598016);    //  262144 f32
    float* k_a  = (float*)(wsb + 1646592);   // 2097152 f32
    short* x    = (short*)(wsb + 10035200);  // 4194304 bf16
    short* wvT  = (short*)(wsb + 18423808);  //  147456 bf16
    short* woT  = (short*)(wsb + 18718720);  //   73728 bf16  (end 18866176)

    k_zero<<<576, 256, 0, stream>>>(q, 147456);  // q + k contiguous
    k_pool<<<1024, 256, 0, stream>>>(inp, q_a, 32);
    k_pool<<<8192, 256, 0, stream>>>(k_ant, k_a, 256);
    k_wtrans<128><<<576, 256, 0, stream>>>(cvw, wvT);
    k_wtrans<64><<<288, 256, 0, stream>>>(cow, woT);
    k_proj<<<dim3(1, 4, 8), 256, 0, stream>>>(q_a, w_q, q);
    k_proj<<<dim3(8, 4, 8), 256, 0, stream>>>(k_a, w_k, k);
    k_attnw<<<32, 64, 0, stream>>>(q, k, tbk, wt);
    k_convv_mfma<<<256, 256, 0, stream>>>(v_ant, wvT, cvb, tbv, wt, x);
    k_convo_mfma<<<256, 256, 0, stream>>>(x, woT, cob, (float*)d_out);
}

// Round 6
// 437.720 us; speedup vs baseline: 4.1926x; 1.6222x over previous
//
#include <hip/hip_runtime.h>
#include <hip/hip_bf16.h>

typedef __hip_bfloat16 bf16;
typedef __attribute__((ext_vector_type(8))) short bf16x8;
typedef __attribute__((ext_vector_type(4))) float f32x4;

constexpr int B_ = 32, S_ = 8, H_ = 32, W_ = 32, C_ = 128;
constexpr int NH_ = 8, KD_ = 512, DKH_ = 64, VF_ = 128, OF_ = 64;
constexpr int QKIN_ = 8192;

static __device__ __forceinline__ short bfbits(float f) {
    bf16 h = __float2bfloat16(f);
    short s;
    __builtin_memcpy(&s, &h, 2);
    return s;
}
static __device__ __forceinline__ unsigned int packbf2(float a, float b) {
    return ((unsigned int)(unsigned short)bfbits(b) << 16) | (unsigned short)bfbits(a);
}

// ---------------- zero fp32 region
__global__ void k_zero(float* __restrict__ p, int n) {
    int i = blockIdx.x * 256 + threadIdx.x;
    if (i < n) p[i] = 0.f;
}

// ---------------- avg pool 4x4 -> flattened (img, 8192) bf16, float4 loads
__global__ void k_pool4(const float* __restrict__ in, short* __restrict__ out, int n_img) {
    int idx = blockIdx.x * 256 + threadIdx.x;
    if (idx >= n_img * 2048) return;
    int c4 = (idx & 31) * 4;
    int pw = (idx >> 5) & 7;
    int ph = (idx >> 8) & 7;
    int img = idx >> 11;
    const float* p = in + (((size_t)img * H_ + ph * 4) * W_ + pw * 4) * C_ + c4;
    float4 s = {0.f, 0.f, 0.f, 0.f};
#pragma unroll
    for (int dy = 0; dy < 4; ++dy)
#pragma unroll
        for (int dx = 0; dx < 4; ++dx) {
            float4 v = *reinterpret_cast<const float4*>(p + (dy * W_ + dx) * C_);
            s.x += v.x; s.y += v.y; s.z += v.z; s.w += v.w;
        }
    uint2 pk;
    pk.x = packbf2(s.x * 0.0625f, s.y * 0.0625f);
    pk.y = packbf2(s.z * 0.0625f, s.w * 0.0625f);
    *reinterpret_cast<uint2*>(out + (size_t)img * QKIN_ + (ph * 8 + pw) * 128 + c4) = pk;
}

// ---------------- transpose+cvt: w[K=8192][N=512] f32 -> wT[N][K] bf16
__global__ __launch_bounds__(256) void k_wT(const float* __restrict__ w,
                                            short* __restrict__ wT) {
    __shared__ float t[64][65];
    int k0 = blockIdx.x * 64, n0 = blockIdx.y * 64;
    int col = threadIdx.x & 63, r4 = threadIdx.x >> 6;
#pragma unroll
    for (int i = 0; i < 16; ++i) {
        int kr = i * 4 + r4;
        t[kr][col] = w[(size_t)(k0 + kr) * KD_ + n0 + col];
    }
    __syncthreads();
    int n = threadIdx.x >> 3, kg = threadIdx.x & 7;
#pragma unroll
    for (int half = 0; half < 2; ++half) {
        int nn = n + half * 32;
        short v[8];
#pragma unroll
        for (int j = 0; j < 8; ++j) v[j] = bfbits(t[kg * 8 + j][nn]);
        *reinterpret_cast<bf16x8*>(wT + (size_t)(n0 + nn) * QKIN_ + k0 + kg * 8) =
            *reinterpret_cast<bf16x8*>(v);
    }
}

// ---------------- MFMA GEMM: out[M,512] += A[M,8192] @ W[8192,512]; WT is N-major bf16
// grid (M/32, 4, 8); block 256 (4 waves). K-tile 1024 per z.
__global__ __launch_bounds__(256) void k_gemm_mfma(const short* __restrict__ A,
                                                   const short* __restrict__ WT,
                                                   float* __restrict__ out) {
    int wave = threadIdx.x >> 6, lane = threadIdx.x & 63;
    int quad = lane >> 4, l15 = lane & 15;
    int m0 = blockIdx.x * 32;
    int n0 = blockIdx.y * 128 + wave * 32;
    int k0 = blockIdx.z * 1024;
    f32x4 acc[2][2];
#pragma unroll
    for (int mt = 0; mt < 2; ++mt)
#pragma unroll
        for (int nt = 0; nt < 2; ++nt) acc[mt][nt] = (f32x4){0.f, 0.f, 0.f, 0.f};
    const short* a0p = A + (size_t)(m0 + l15) * QKIN_;
    const short* a1p = a0p + 16 * QKIN_;
    const short* b0p = WT + (size_t)(n0 + l15) * QKIN_;
    const short* b1p = b0p + 16 * QKIN_;
    for (int kk = k0 + quad * 8; kk < k0 + 1024; kk += 32) {
        bf16x8 a0 = *reinterpret_cast<const bf16x8*>(a0p + kk);
        bf16x8 a1 = *reinterpret_cast<const bf16x8*>(a1p + kk);
        bf16x8 b0 = *reinterpret_cast<const bf16x8*>(b0p + kk);
        bf16x8 b1 = *reinterpret_cast<const bf16x8*>(b1p + kk);
        acc[0][0] = __builtin_amdgcn_mfma_f32_16x16x32_bf16(a0, b0, acc[0][0], 0, 0, 0);
        acc[0][1] = __builtin_amdgcn_mfma_f32_16x16x32_bf16(a0, b1, acc[0][1], 0, 0, 0);
        acc[1][0] = __builtin_amdgcn_mfma_f32_16x16x32_bf16(a1, b0, acc[1][0], 0, 0, 0);
        acc[1][1] = __builtin_amdgcn_mfma_f32_16x16x32_bf16(a1, b1, acc[1][1], 0, 0, 0);
    }
#pragma unroll
    for (int mt = 0; mt < 2; ++mt)
#pragma unroll
        for (int nt = 0; nt < 2; ++nt)
#pragma unroll
            for (int reg = 0; reg < 4; ++reg)
                atomicAdd(&out[(size_t)(m0 + mt * 16 + quad * 4 + reg) * KD_ +
                               n0 + nt * 16 + l15],
                          acc[mt][nt][reg]);
}

// ---------------- logits + softmax -> weights (B, NH, S) fp32
__global__ void k_attnw(const float* __restrict__ q, const float* __restrict__ k,
                        const float* __restrict__ table_k, float* __restrict__ wt) {
    int b = blockIdx.x;
    int t = threadIdx.x;
    int h = t >> 3, s = t & 7;
    int zi = (s < 4) ? 0 : (s - 4);
    const float* qp = q + (size_t)b * KD_ + h * DKH_;
    const float* kp = k + ((size_t)b * S_ + s) * KD_ + h * DKH_;
    const float* zp = table_k + (size_t)zi * DKH_;
    float dot = 0.f;
    for (int d = 0; d < DKH_; ++d)
        dot += qp[d] * (kp[d] + zp[d]);
    dot *= 0.125f;
    float m = dot;
    for (int msk = 1; msk < 8; msk <<= 1) m = fmaxf(m, __shfl_xor(m, msk));
    float e = expf(dot - m);
    float sum = e;
    for (int msk = 1; msk < 8; msk <<= 1) sum += __shfl_xor(sum, msk);
    wt[((size_t)b * NH_ + h) * S_ + s] = e / sum;
}

// ---------------- conv weight transpose: [tap][ci][CO] f32 -> [tap][co][CI] bf16
template <int CO>
__global__ void k_wtrans(const float* __restrict__ in, short* __restrict__ out) {
    int idx = blockIdx.x * 256 + threadIdx.x;
    if (idx >= 9 * 128 * CO) return;
    int tap = idx / (128 * CO);
    int rem = idx % (128 * CO);
    int co = rem / 128;
    int ci = rem % 128;
    out[idx] = bfbits(in[((size_t)tap * 128 + ci) * CO + co]);
}

// ---------------- fused mix + conv_v via MFMA. block=(b,h), 4 waves.
__global__ __launch_bounds__(256) void k_convv_mfma(
    const float* __restrict__ v_ant, const short* __restrict__ wvT,
    const float* __restrict__ bias, const float* __restrict__ tbv,
    const float* __restrict__ wt, short* __restrict__ x) {
    __shared__ short strip[6 * 32 * 136];  // 52224 B
    int b = blockIdx.x >> 3, h = blockIdx.x & 7;
    int y0 = 4 * h;
    const float* wtb = wt + (size_t)(b * NH_ + h) * S_;
    float w8[8];
#pragma unroll
    for (int kk = 0; kk < 8; ++kk) w8[kk] = wtb[kk];
    // phase 1: softmax-mix 6 halo rows -> bf16 strip (float4 loads)
    for (int i = threadIdx.x; i < 6 * 1024; i += 256) {
        int r = i >> 10, rem = i & 1023;           // rem = px*32 + ci/4
        int yimg = y0 - 1 + r;
        float4 s = {0.f, 0.f, 0.f, 0.f};
        if (0 <= yimg && yimg < H_) {
            const float* base = v_ant + (size_t)b * 1048576 + yimg * 4096 + rem * 4;
#pragma unroll
            for (int kk = 0; kk < 8; ++kk) {
                float4 v = *reinterpret_cast<const float4*>(base + (size_t)kk * 131072);
                s.x = fmaf(w8[kk], v.x, s.x);
                s.y = fmaf(w8[kk], v.y, s.y);
                s.z = fmaf(w8[kk], v.z, s.z);
                s.w = fmaf(w8[kk], v.w, s.w);
            }
        }
        int px = rem >> 5, cg = rem & 31;
        uint2 pk;
        pk.x = packbf2(s.x, s.y);
        pk.y = packbf2(s.z, s.w);
        *reinterpret_cast<uint2*>(&strip[(r * 32 + px) * 136 + cg * 4]) = pk;
    }
    __syncthreads();
    // phase 2: GEMM M=128(4 rows x 32 px), N=128 co, K=1152
    int wave = threadIdx.x >> 6, lane = threadIdx.x & 63;
    int quad = lane >> 4, l15 = lane & 15;
    int n0 = wave * 32;
    f32x4 acc[8][2];
#pragma unroll
    for (int mt = 0; mt < 8; ++mt)
#pragma unroll
        for (int nt = 0; nt < 2; ++nt) acc[mt][nt] = (f32x4){0.f, 0.f, 0.f, 0.f};
    const bf16x8 zero8 = (bf16x8)0;
    for (int kc = 0; kc < 36; ++kc) {
        int tap = kc >> 2;
        int ci0 = (kc & 3) * 32 + quad * 8;
        int ky = tap / 3, dx = tap % 3;
        bf16x8 bfr[2];
#pragma unroll
        for (int nt = 0; nt < 2; ++nt) {
            int co = n0 + nt * 16 + l15;
            bfr[nt] = *reinterpret_cast<const bf16x8*>(
                wvT + ((size_t)tap * 128 + co) * 128 + ci0);
        }
#pragma unroll
        for (int mt = 0; mt < 8; ++mt) {
            int jout = mt >> 1, half = mt & 1;
            int r = jout + ky;
            int pxg = half * 16 + l15 + dx - 1;
            bf16x8 afr = zero8;
            if (pxg >= 0 && pxg < 32)
                afr = *reinterpret_cast<const bf16x8*>(
                    &strip[(r * 32 + pxg) * 136 + ci0]);
            acc[mt][0] = __builtin_amdgcn_mfma_f32_16x16x32_bf16(afr, bfr[0], acc[mt][0], 0, 0, 0);
            acc[mt][1] = __builtin_amdgcn_mfma_f32_16x16x32_bf16(afr, bfr[1], acc[mt][1], 0, 0, 0);
        }
    }
    float cw[4];
    cw[0] = w8[0] + w8[1] + w8[2] + w8[3] + w8[4];
    cw[1] = w8[5];
    cw[2] = w8[6];
    cw[3] = w8[7];
#pragma unroll
    for (int mt = 0; mt < 8; ++mt) {
        int jout = mt >> 1, half = mt & 1;
#pragma unroll
        for (int nt = 0; nt < 2; ++nt) {
            int co = n0 + nt * 16 + l15;
            float bv = bias[co];
#pragma unroll
            for (int reg = 0; reg < 4; ++reg) {
                int px = half * 16 + quad * 4 + reg;
                int d = jout * 4096 + px * 128 + co;
                float v = acc[mt][nt][reg] + bv;
                v = fmaf(cw[0], tbv[d], v);
                v = fmaf(cw[1], tbv[16384 + d], v);
                v = fmaf(cw[2], tbv[32768 + d], v);
                v = fmaf(cw[3], tbv[49152 + d], v);
                x[(((size_t)b * H_ + y0 + jout) * W_ + px) * C_ + co] = bfbits(v);
            }
        }
    }
}

// ---------------- conv_o via MFMA. block=(b, rowgroup of 4), 4 waves.
__global__ __launch_bounds__(256) void k_convo_mfma(
    const short* __restrict__ x, const short* __restrict__ woT,
    const float* __restrict__ bias, float* __restrict__ out) {
    __shared__ short strip[6 * 32 * 136];
    int b = blockIdx.x >> 3, rg = blockIdx.x & 7;
    int y0 = 4 * rg;
    for (int i = threadIdx.x; i < 6 * 1024; i += 256) {
        int r = i >> 10, rem = i & 1023;
        int yimg = y0 - 1 + r;
        uint2 v = {0u, 0u};
        if (0 <= yimg && yimg < H_)
            v = *reinterpret_cast<const uint2*>(
                x + (size_t)b * 131072 + yimg * 4096 + rem * 4);
        int px = rem >> 5, cg = rem & 31;
        *reinterpret_cast<uint2*>(&strip[(r * 32 + px) * 136 + cg * 4]) = v;
    }
    __syncthreads();
    int wave = threadIdx.x >> 6, lane = threadIdx.x & 63;
    int quad = lane >> 4, l15 = lane & 15;
    int co = wave * 16 + l15;
    f32x4 acc[8];
#pragma unroll
    for (int mt = 0; mt < 8; ++mt) acc[mt] = (f32x4){0.f, 0.f, 0.f, 0.f};
    const bf16x8 zero8 = (bf16x8)0;
    for (int kc = 0; kc < 36; ++kc) {
        int tap = kc >> 2;
        int ci0 = (kc & 3) * 32 + quad * 8;
        int ky = tap / 3, dx = tap % 3;
        bf16x8 bfr = *reinterpret_cast<const bf16x8*>(
            woT + ((size_t)tap * 64 + co) * 128 + ci0);
#pragma unroll
        for (int mt = 0; mt < 8; ++mt) {
            int jout = mt >> 1, half = mt & 1;
            int r = jout + ky;
            int pxg = half * 16 + l15 + dx - 1;
            bf16x8 afr = zero8;
            if (pxg >= 0 && pxg < 32)
                afr = *reinterpret_cast<const bf16x8*>(
                    &strip[(r * 32 + pxg) * 136 + ci0]);
            acc[mt] = __builtin_amdgcn_mfma_f32_16x16x32_bf16(afr, bfr, acc[mt], 0, 0, 0);
        }
    }
    float bv = bias[co];
#pragma unroll
    for (int mt = 0; mt < 8; ++mt) {
        int jout = mt >> 1, half = mt & 1;
#pragma unroll
        for (int reg = 0; reg < 4; ++reg) {
            int px = half * 16 + quad * 4 + reg;
            out[(((size_t)b * H_ + y0 + jout) * W_ + px) * OF_ + co] = acc[mt][reg] + bv;
        }
    }
}

extern "C" void kernel_launch(void* const* d_in, const int* in_sizes, int n_in,
                              void* d_out, int out_size, void* d_ws, size_t ws_size,
                              hipStream_t stream) {
    const float* inp   = (const float*)d_in[0];
    const float* k_ant = (const float*)d_in[1];
    const float* v_ant = (const float*)d_in[2];
    const float* w_q   = (const float*)d_in[3];
    const float* w_k   = (const float*)d_in[4];
    const float* cvw   = (const float*)d_in[5];
    const float* cvb   = (const float*)d_in[6];
    const float* cow   = (const float*)d_in[7];
    const float* cob   = (const float*)d_in[8];
    const float* tbk   = (const float*)d_in[9];
    const float* tbv   = (const float*)d_in[10];

    // ws layout (bytes), total ~21.5 MB. x aliases wqT (wqT's last read — the q GEMM —
    // precedes x's first write in stream order).
    char* wsb = (char*)d_ws;
    float* q    = (float*)(wsb + 0);         //   16384 f32
    float* k    = (float*)(wsb + 65536);     //  131072 f32
    float* wt   = (float*)(wsb + 589824);    //    2048 f32
    short* q_a  = (short*)(wsb + 598016);    //  262144 bf16
    short* k_a  = (short*)(wsb + 1122304);   // 2097152 bf16
    short* wvT  = (short*)(wsb + 5316608);   //  147456 bf16
    short* woT  = (short*)(wsb + 5611520);   //   73728 bf16
    short* wkT  = (short*)(wsb + 5758976);   // 4194304 bf16
    short* wqT  = (short*)(wsb + 14147584);  // 4194304 bf16
    short* x    = wqT;                       // alias (see above)

    k_zero<<<576, 256, 0, stream>>>(q, 147456);     // q + k contiguous
    k_pool4<<<256, 256, 0, stream>>>(inp, q_a, 32);
    k_pool4<<<2048, 256, 0, stream>>>(k_ant, k_a, 256);
    k_wT<<<dim3(128, 8), 256, 0, stream>>>(w_q, wqT);
    k_wT<<<dim3(128, 8), 256, 0, stream>>>(w_k, wkT);
    k_wtrans<128><<<576, 256, 0, stream>>>(cvw, wvT);
    k_wtrans<64><<<288, 256, 0, stream>>>(cow, woT);
    k_gemm_mfma<<<dim3(1, 4, 8), 256, 0, stream>>>(q_a, wqT, q);
    k_gemm_mfma<<<dim3(8, 4, 8), 256, 0, stream>>>(k_a, wkT, k);
    k_attnw<<<32, 64, 0, stream>>>(q, k, tbk, wt);
    k_convv_mfma<<<256, 256, 0, stream>>>(v_ant, wvT, cvb, tbv, wt, x);
    k_convo_mfma<<<256, 256, 0, stream>>>(x, woT, cob, (float*)d_out);
}